// Round 4
// baseline (642.596 us; speedup 1.0000x reference)
//
#include <hip/hip_runtime.h>
#include <hip/hip_bf16.h>

// Problem constants
#define B 2048
#define D 1024
#define H 64
#define K 3
#define SKIP 4
#define DOUT (D - SKIP)   // 1020
#define T 128             // number of D-chunks
#define DC (D / T)        // 8 dims per chunk
#define BG 4              // b-groups (waves) per k_main block

// Workspace layout (float slots):
//   S   : T*B*H bf16 = 16,777,216 ushorts -> 8,388,608 float slots
//   Vp  : D*H*12  =   786,432  (packed V: [mean0..2, std0..2, alpha0..2, pad3])
//   Wt  : D*H     =    65,536  (W transposed to [d][h])
//   xT  : D*B     = 2,097,152  (x transposed to [d][b])
#define WS_S  0
#define WS_VP (T * B * H / 2)
#define WS_WT (WS_VP + D * H * 12)
#define WS_XT (WS_WT + D * H)

__device__ __forceinline__ unsigned short f2bf(float f) {
    union { float f; unsigned int u; } v; v.f = f;
    unsigned int r = (v.u + 0x7FFFu + ((v.u >> 16) & 1u)) >> 16;  // RNE
    return (unsigned short)r;
}
__device__ __forceinline__ float bflo(unsigned int u) { return __uint_as_float(u << 16); }
__device__ __forceinline__ float bfhi(unsigned int u) { return __uint_as_float(u & 0xFFFF0000u); }

// ---------------------------------------------------------------------------
// Pack V into Vp[d][h][12] (fully coalesced both sides)
// ---------------------------------------------------------------------------
__global__ __launch_bounds__(256) void k_pack(const float* __restrict__ Vm,
                                              const float* __restrict__ Va,
                                              const float* __restrict__ Vs,
                                              float* __restrict__ Vp) {
    int idx = blockIdx.x * 256 + threadIdx.x;  // 0 .. D*H-1, idx = d*64 + h
    float* o = Vp + (size_t)idx * 12;
#pragma unroll
    for (int k = 0; k < 3; ++k) o[k]     = Vm[idx * 3 + k];
#pragma unroll
    for (int k = 0; k < 3; ++k) o[3 + k] = Vs[idx * 3 + k];
#pragma unroll
    for (int k = 0; k < 3; ++k) o[6 + k] = Va[idx * 3 + k];
    o[9] = 0.f; o[10] = 0.f; o[11] = 0.f;
}

// ---------------------------------------------------------------------------
// Transpose W[H=64][D] -> Wt[D][H] via LDS tile. grid (D/64, 1), block 256.
// ---------------------------------------------------------------------------
__global__ __launch_bounds__(256) void k_wt(const float* __restrict__ W,
                                            float* __restrict__ Wt) {
    __shared__ float tile[64][65];
    const int tx = threadIdx.x & 63;
    const int ty = threadIdx.x >> 6;
    const int d0 = blockIdx.x * 64;
#pragma unroll
    for (int r = 0; r < 64; r += 4)
        tile[r + ty][tx] = W[(size_t)(r + ty) * D + d0 + tx];
    __syncthreads();
#pragma unroll
    for (int r = 0; r < 64; r += 4)
        Wt[(size_t)(d0 + r + ty) * H + tx] = tile[tx][r + ty];
}

// ---------------------------------------------------------------------------
// Transpose x[B][D] -> xT[D][B] via 64x64 LDS tile. grid (D/64, B/64), block 256.
// ---------------------------------------------------------------------------
__global__ __launch_bounds__(256) void k_xt(const float* __restrict__ x,
                                            float* __restrict__ xT) {
    __shared__ float tile[64][65];
    const int tx = threadIdx.x & 63;
    const int ty = threadIdx.x >> 6;
    const int d0 = blockIdx.x * 64;
    const int b0 = blockIdx.y * 64;
#pragma unroll
    for (int r = 0; r < 64; r += 4)
        tile[r + ty][tx] = x[(size_t)(b0 + r + ty) * D + d0 + tx];
    __syncthreads();
#pragma unroll
    for (int r = 0; r < 64; r += 4)
        xT[(size_t)(d0 + r + ty) * B + b0 + tx] = tile[tx][r + ty];
}

// ---------------------------------------------------------------------------
// Prefix: one wave per b (lane = h). Walk D sequentially; every DC dims store
// an exclusive bf16 checkpoint S[t][b][h]. x row consumed 64-wide per lane,
// broadcast via __shfl (v_readlane). W reads are per-lane coalesced.
// ---------------------------------------------------------------------------
__global__ __launch_bounds__(256) void k_prefix(const float* __restrict__ x,
                                                const float* __restrict__ Wt,
                                                const float* __restrict__ c,
                                                unsigned short* __restrict__ S) {
    const int lane = threadIdx.x & 63;
    const int w    = threadIdx.x >> 6;
    const int b    = blockIdx.x * 4 + w;
    float run = c[lane];
    const float* xr = x + (size_t)b * D;
    for (int c16 = 0; c16 < 16; ++c16) {
        const float xv = xr[c16 * 64 + lane];   // lane l holds x[b, c16*64+l]
#pragma unroll
        for (int sub = 0; sub < 8; ++sub) {
            const int t = c16 * 8 + sub;
            S[((size_t)t * B + b) * H + lane] = f2bf(run);
#pragma unroll
            for (int dl = 0; dl < 8; ++dl) {
                const int d = c16 * 64 + sub * 8 + dl;
                const float wv = Wt[(size_t)d * H + lane];
                const float xs = __shfl(xv, sub * 8 + dl);
                run = fmaf(xs, wv, run);
            }
        }
    }
}

// ---------------------------------------------------------------------------
// Main pass: block = 4 waves = 4 b-groups at one t-chunk (8 dims).
// Vp/Wt/bias chunk staged in LDS (26KB); per-lane state a[64] in VGPRs.
// grid (B/256, T), block 256.
// ---------------------------------------------------------------------------
__global__ __launch_bounds__(256, 3) void k_main(const float* __restrict__ xT,
                                                 const unsigned short* __restrict__ S,
                                                 const float* __restrict__ Vp,
                                                 const float* __restrict__ Wt,
                                                 const float* __restrict__ bm,
                                                 const float* __restrict__ ba,
                                                 const float* __restrict__ bs,
                                                 float* __restrict__ out) {
    __shared__ float vs[DC * H * 12];   // 6144 floats = 24KB
    __shared__ float wsh[DC * H];       // 512 floats = 2KB
    __shared__ float bsh[96];           // 24 bm | 24 bs | 24 ba

    const int tid  = threadIdx.x;
    const int lane = tid & 63;
    const int w    = tid >> 6;
    const int t    = blockIdx.y;
    const int d0   = t * DC;
    const int b    = (blockIdx.x * BG + w) * 64 + lane;

    // ---- stage chunk into LDS (coalesced) ----
    {
        const float4* vsrc = (const float4*)(Vp + (size_t)d0 * (H * 12));
        float4* vdst = (float4*)vs;
#pragma unroll
        for (int q = 0; q < 6; ++q) vdst[q * 256 + tid] = vsrc[q * 256 + tid];
        wsh[tid]       = Wt[(size_t)d0 * H + tid];
        wsh[tid + 256] = Wt[(size_t)d0 * H + 256 + tid];
        if (tid < 24)      bsh[tid]      = bm[d0 * 3 + tid];
        else if (tid < 48) bsh[tid]      = bs[d0 * 3 + (tid - 24)];
        else if (tid < 72) bsh[tid]      = ba[d0 * 3 + (tid - 48)];
    }

    // ---- load bf16 checkpoint state: 64 values per lane (8 x uint4 = 8x8 bf16) ----
    float a[H];
    {
        const uint4* cp = (const uint4*)(S + ((size_t)t * B + b) * H);
#pragma unroll
        for (int q = 0; q < 8; ++q) {
            uint4 u = cp[q];
            a[q * 8 + 0] = bflo(u.x); a[q * 8 + 1] = bfhi(u.x);
            a[q * 8 + 2] = bflo(u.y); a[q * 8 + 3] = bfhi(u.y);
            a[q * 8 + 4] = bflo(u.z); a[q * 8 + 5] = bfhi(u.z);
            a[q * 8 + 6] = bflo(u.w); a[q * 8 + 7] = bfhi(u.w);
        }
    }
    __syncthreads();

    float* om = out + (size_t)b * DOUT * 3;
    float* os = om + (size_t)B * DOUT * 3;
    float* oa = os + (size_t)B * DOUT * 3;

    float bufm[12], bufs[12], bufa[12];

#pragma unroll
    for (int g = 0; g < 2; ++g) {
        const bool emit = (t > 0) || (g == 1);
#pragma unroll
        for (int dl4 = 0; dl4 < 4; ++dl4) {
            const int dl = g * 4 + dl4;
            const int d  = d0 + dl;
            const float xv = xT[(size_t)d * B + b];

            if (emit) {
                float acc[9];
#pragma unroll
                for (int k = 0; k < 9; ++k) acc[k] = 0.f;
                const float* vp = vs + dl * (H * 12);
#pragma unroll
                for (int h = 0; h < H; ++h) {
                    const float hv = fmaxf(a[h], 0.f);
                    const float4 v0 = *(const float4*)(vp + h * 12);
                    const float4 v1 = *(const float4*)(vp + h * 12 + 4);
                    const float4 v2 = *(const float4*)(vp + h * 12 + 8);
                    acc[0] = fmaf(hv, v0.x, acc[0]);
                    acc[1] = fmaf(hv, v0.y, acc[1]);
                    acc[2] = fmaf(hv, v0.z, acc[2]);
                    acc[3] = fmaf(hv, v0.w, acc[3]);
                    acc[4] = fmaf(hv, v1.x, acc[4]);
                    acc[5] = fmaf(hv, v1.y, acc[5]);
                    acc[6] = fmaf(hv, v1.z, acc[6]);
                    acc[7] = fmaf(hv, v1.w, acc[7]);
                    acc[8] = fmaf(hv, v2.x, acc[8]);
                }
                // mean
                bufm[dl4 * 3 + 0] = acc[0] + bsh[dl * 3 + 0];
                bufm[dl4 * 3 + 1] = acc[1] + bsh[dl * 3 + 1];
                bufm[dl4 * 3 + 2] = acc[2] + bsh[dl * 3 + 2];
                // std = sigmoid(z)*2 + 0.6
#pragma unroll
                for (int k = 0; k < 3; ++k) {
                    float z = acc[3 + k] + bsh[24 + dl * 3 + k];
                    bufs[dl4 * 3 + k] = 2.f * __builtin_amdgcn_rcpf(1.f + __expf(-z)) + 0.6f;
                }
                // alpha = softmax
                {
                    float z0 = acc[6] + bsh[48 + dl * 3 + 0];
                    float z1 = acc[7] + bsh[48 + dl * 3 + 1];
                    float z2 = acc[8] + bsh[48 + dl * 3 + 2];
                    float mx = fmaxf(z0, fmaxf(z1, z2));
                    float e0 = __expf(z0 - mx);
                    float e1 = __expf(z1 - mx);
                    float e2 = __expf(z2 - mx);
                    float inv = __builtin_amdgcn_rcpf(e0 + e1 + e2);
                    bufa[dl4 * 3 + 0] = e0 * inv;
                    bufa[dl4 * 3 + 1] = e1 * inv;
                    bufa[dl4 * 3 + 2] = e2 * inv;
                }
            }

            // a[h] += x[b,d] * W[h,d]
            const float* wp = wsh + dl * H;
#pragma unroll
            for (int h = 0; h < H; h += 4) {
                float4 wv = *(const float4*)(wp + h);
                a[h]     = fmaf(xv, wv.x, a[h]);
                a[h + 1] = fmaf(xv, wv.y, a[h + 1]);
                a[h + 2] = fmaf(xv, wv.z, a[h + 2]);
                a[h + 3] = fmaf(xv, wv.w, a[h + 3]);
            }
        }
        if (emit) {
            const size_t off = (size_t)(d0 + g * 4 - 4) * 3;   // 16B-aligned
#pragma unroll
            for (int q = 0; q < 3; ++q) {
                *(float4*)(om + off + q * 4) = make_float4(bufm[q*4], bufm[q*4+1], bufm[q*4+2], bufm[q*4+3]);
                *(float4*)(os + off + q * 4) = make_float4(bufs[q*4], bufs[q*4+1], bufs[q*4+2], bufs[q*4+3]);
                *(float4*)(oa + off + q * 4) = make_float4(bufa[q*4], bufa[q*4+1], bufa[q*4+2], bufa[q*4+3]);
            }
        }
    }
}

// ---------------------------------------------------------------------------
extern "C" void kernel_launch(void* const* d_in, const int* in_sizes, int n_in,
                              void* d_out, int out_size, void* d_ws, size_t ws_size,
                              hipStream_t stream) {
    const float* x  = (const float*)d_in[0];   // [B, D]
    const float* W  = (const float*)d_in[1];   // [H, D]
    const float* c  = (const float*)d_in[2];   // [1, H]
    const float* Vm = (const float*)d_in[3];   // [D, H, K]
    const float* Va = (const float*)d_in[4];   // [D, H, K]
    const float* Vs = (const float*)d_in[5];   // [D, H, K]
    const float* bm = (const float*)d_in[6];   // [D, K]
    const float* ba = (const float*)d_in[7];   // [D, K]
    const float* bs = (const float*)d_in[8];   // [D, K]
    float* out = (float*)d_out;

    float* wsf = (float*)d_ws;
    unsigned short* S = (unsigned short*)(wsf + WS_S);
    float* Vp  = wsf + WS_VP;
    float* Wt  = wsf + WS_WT;
    float* xT  = wsf + WS_XT;

    k_pack<<<dim3(D * H / 256), dim3(256), 0, stream>>>(Vm, Va, Vs, Vp);
    k_wt<<<dim3(D / 64), dim3(256), 0, stream>>>(W, Wt);
    k_xt<<<dim3(D / 64, B / 64), dim3(256), 0, stream>>>(x, xT);
    k_prefix<<<dim3(B / 4), dim3(256), 0, stream>>>(x, Wt, c, S);
    k_main<<<dim3(B / (64 * BG), T), dim3(256), 0, stream>>>(xT, S, Vp, Wt, bm, ba, bs, out);
}

// Round 7
// 180.954 us; speedup vs baseline: 3.5512x; 3.5512x over previous
//
#include <hip/hip_runtime.h>
#include <hip/hip_bf16.h>

// Problem constants
#define B 2048
#define D 1024
#define H 64
#define K 3
#define DOUT (D - 4)      // 1020
#define T 64              // chunks; chunk t anchored at dstart = 16t+4
#define DC 16             // dims per chunk (last chunk: 12)

#if __has_builtin(__builtin_amdgcn_fdot2) && __has_builtin(__builtin_amdgcn_cvt_pkrtz)
#define HAS_DOT2 1
#else
#define HAS_DOT2 0
#endif
typedef __fp16 half2_t __attribute__((ext_vector_type(2)));

// Workspace layout (float slots):
//   S   : T*B*H f16  = 8,388,608 halfs  -> 4,194,304 float slots
//   Vp  : D*32hp*12 dwords = 393,216    (packed f16-pair V)
//   Wt  : D*H = 65,536                  (W transposed to [d][h], f32)
//   xT  : D*B = 2,097,152               (x transposed to [d][b], f32)
#define WS_S  0
#define WS_VP (T * B * H / 2)
#define WS_WT (WS_VP + D * 32 * 12)
#define WS_XT (WS_WT + D * H)

__device__ __forceinline__ unsigned short f2h_u(float f) {
    union { _Float16 h; unsigned short u; } v; v.h = (_Float16)f; return v.u;
}
__device__ __forceinline__ float h2f_u(unsigned short s) {
    union { unsigned short u; _Float16 h; } v; v.u = s; return (float)v.h;
}
__device__ __forceinline__ unsigned packh2(float lo, float hi) {
    union { _Float16 h[2]; unsigned u; } v;
    v.h[0] = (_Float16)lo; v.h[1] = (_Float16)hi; return v.u;
}
__device__ __forceinline__ half2_t as_h2(unsigned u) {
    union { unsigned u; half2_t h; } v; v.u = u; return v.h;
}

// ---------------------------------------------------------------------------
// Pack V into f16 pairs: Vp[d][hp][12 dwords]; dword q: k=q mean, q-3 std,
// q-6 alpha; lo half = h=2hp, hi half = h=2hp+1. q=9..11 pad.
// ---------------------------------------------------------------------------
__global__ __launch_bounds__(256) void k_pack(const float* __restrict__ Vm,
                                              const float* __restrict__ Va,
                                              const float* __restrict__ Vs,
                                              unsigned* __restrict__ Vp) {
    int idx = blockIdx.x * 256 + threadIdx.x;  // 0 .. D*32-1: d*32 + hp
    const size_t hbase = ((size_t)(idx >> 5) * 64 + 2 * (idx & 31)) * 3;
    const float* pm = Vm + hbase;
    const float* ps = Vs + hbase;
    const float* pa = Va + hbase;
    unsigned o[12];
#pragma unroll
    for (int k = 0; k < 3; ++k) {
        o[k]     = packh2(pm[k], pm[3 + k]);
        o[3 + k] = packh2(ps[k], ps[3 + k]);
        o[6 + k] = packh2(pa[k], pa[3 + k]);
    }
    o[9] = 0u; o[10] = 0u; o[11] = 0u;
    uint4* dst = (uint4*)(Vp + (size_t)idx * 12);
    dst[0] = make_uint4(o[0], o[1], o[2], o[3]);
    dst[1] = make_uint4(o[4], o[5], o[6], o[7]);
    dst[2] = make_uint4(o[8], o[9], o[10], o[11]);
}

// ---------------------------------------------------------------------------
// Transpose W[H][D] -> Wt[D][H] (f32) via LDS tile. grid (D/64), block 256.
// ---------------------------------------------------------------------------
__global__ __launch_bounds__(256) void k_wt(const float* __restrict__ W,
                                            float* __restrict__ Wt) {
    __shared__ float tile[64][65];
    const int tx = threadIdx.x & 63;
    const int ty = threadIdx.x >> 6;
    const int d0 = blockIdx.x * 64;
#pragma unroll
    for (int r = 0; r < 64; r += 4)
        tile[r + ty][tx] = W[(size_t)(r + ty) * D + d0 + tx];
    __syncthreads();
#pragma unroll
    for (int r = 0; r < 64; r += 4)
        Wt[(size_t)(d0 + r + ty) * H + tx] = tile[tx][r + ty];
}

// ---------------------------------------------------------------------------
// Transpose x[B][D] -> xT[D][B] via LDS tile. grid (D/64, B/64), block 256.
// ---------------------------------------------------------------------------
__global__ __launch_bounds__(256) void k_xt(const float* __restrict__ x,
                                            float* __restrict__ xT) {
    __shared__ float tile[64][65];
    const int tx = threadIdx.x & 63;
    const int ty = threadIdx.x >> 6;
    const int d0 = blockIdx.x * 64;
    const int b0 = blockIdx.y * 64;
#pragma unroll
    for (int r = 0; r < 64; r += 4)
        tile[r + ty][tx] = x[(size_t)(b0 + r + ty) * D + d0 + tx];
    __syncthreads();
#pragma unroll
    for (int r = 0; r < 64; r += 4)
        xT[(size_t)(d0 + r + ty) * B + b0 + tx] = tile[tx][r + ty];
}

// ---------------------------------------------------------------------------
// Prefix: wave per b (lane = h). W tiles (64 dims) staged in LDS TRANSPOSED
// ([h][d], read straight from W which is already [h][d]); x broadcast via LDS.
// Emit f16 checkpoint S[t][b][h] = c + sum_{j<16t+4} when reaching d = 16t+4.
// grid (B/8), block 512 (8 waves = 8 b).
// ---------------------------------------------------------------------------
__global__ __launch_bounds__(512) void k_prefix(const float* __restrict__ x,
                                                const float* __restrict__ W,
                                                const float* __restrict__ cvec,
                                                unsigned short* __restrict__ S) {
    __shared__ float wt[64 * 68];   // [h][d] padded (68 = 4*17 keeps 16B align)
    __shared__ float xl[8 * 64];
    const int tid  = threadIdx.x;
    const int lane = tid & 63;      // h
    const int w    = tid >> 6;
    const int b    = blockIdx.x * 8 + w;

    float run = cvec[lane];
    for (int c = 0; c < 16; ++c) {
        __syncthreads();
        // stage W tile: thread -> (h = tid>>3, dc = (tid&7)*8), two float4
        {
            const int h = tid >> 3, dc = (tid & 7) * 8;
            const float* src = W + (size_t)h * D + c * 64 + dc;
            float4 v0 = *(const float4*)src;
            float4 v1 = *(const float4*)(src + 4);
            float* dst = wt + h * 68 + dc;
            *(float4*)dst = v0;
            *(float4*)(dst + 4) = v1;
        }
        xl[w * 64 + lane] = x[(size_t)b * D + c * 64 + lane];
        __syncthreads();
#pragma unroll
        for (int dg = 0; dg < 16; ++dg) {
            if ((dg & 3) == 1) {   // d_local = dg*4 in {4,20,36,52} -> emit
                const int t = 4 * c + (dg >> 2);
                S[((size_t)t * B + b) * H + lane] = f2h_u(run);
            }
            float4 w4 = *(const float4*)(wt + lane * 68 + dg * 4);
            float4 x4 = *(const float4*)(xl + w * 64 + dg * 4);
            run = fmaf(x4.x, w4.x, run);
            run = fmaf(x4.y, w4.y, run);
            run = fmaf(x4.z, w4.z, run);
            run = fmaf(x4.w, w4.w, run);
        }
    }
}

// ---------------------------------------------------------------------------
// Main: block = 4 waves = 256 b at chunk t (dims 16t+4 .. 16t+19, last chunk 12).
// V (f16 pairs) + W + biases staged in LDS; state a[64] in VGPRs; matvec via
// v_dot2_f32_f16; outputs flushed as aligned 48B quarters (192B/run total).
// grid (B/256, T), block 256.
// ---------------------------------------------------------------------------
__global__ __launch_bounds__(256, 2) void k_main(const float* __restrict__ xT,
                                                 const unsigned short* __restrict__ S,
                                                 const unsigned* __restrict__ Vp,
                                                 const float* __restrict__ Wt,
                                                 const float* __restrict__ bm,
                                                 const float* __restrict__ ba,
                                                 const float* __restrict__ bs,
                                                 float* __restrict__ out) {
    __shared__ unsigned vsh[DC * 32 * 12];  // 6144 dwords = 24KB
    __shared__ float    wsh[DC * H];        // 1024 floats = 4KB
    __shared__ float    bsh[DC * 9];        // [dl][{m0..2,s0..2,a0..2}]

    const int tid    = threadIdx.x;
    const int lane   = tid & 63;
    const int w      = tid >> 6;
    const int t      = blockIdx.y;
    const int dstart = 16 * t + 4;
    const int b      = (blockIdx.x * 4 + w) * 64 + lane;
    const int dvalid = D - dstart;          // >=12 always; <16 only at t=63

    // ---- stage chunk ----
    {
        const uint4* vsrc = (const uint4*)(Vp + (size_t)dstart * 384);
        uint4* vdst = (uint4*)vsh;
#pragma unroll
        for (int q = 0; q < 6; ++q) {
            const int j = q * 256 + tid;
            if (j * 4 < dvalid * 384) vdst[j] = vsrc[j];
        }
#pragma unroll
        for (int q = 0; q < 4; ++q) {
            const int idx = q * 256 + tid;
            if (idx < dvalid * 64) wsh[idx] = Wt[(size_t)dstart * 64 + idx];
        }
        if (tid < DC * 9) {
            const int dl = tid / 9, r = tid % 9;
            const int d = dstart + dl;
            if (d < D) {
                const float* p = (r < 3) ? (bm + (size_t)d * 3 + r)
                               : (r < 6) ? (bs + (size_t)d * 3 + (r - 3))
                                         : (ba + (size_t)d * 3 + (r - 6));
                bsh[tid] = *p;
            }
        }
    }

    // ---- load f16 checkpoint: 64 halfs per lane ----
    float a[H];
    {
        const uint4* cp = (const uint4*)(S + ((size_t)t * B + b) * H);
#pragma unroll
        for (int q = 0; q < 8; ++q) {
            uint4 u = cp[q];
            a[q * 8 + 0] = h2f_u((unsigned short)(u.x & 0xffff));
            a[q * 8 + 1] = h2f_u((unsigned short)(u.x >> 16));
            a[q * 8 + 2] = h2f_u((unsigned short)(u.y & 0xffff));
            a[q * 8 + 3] = h2f_u((unsigned short)(u.y >> 16));
            a[q * 8 + 4] = h2f_u((unsigned short)(u.z & 0xffff));
            a[q * 8 + 5] = h2f_u((unsigned short)(u.z >> 16));
            a[q * 8 + 6] = h2f_u((unsigned short)(u.w & 0xffff));
            a[q * 8 + 7] = h2f_u((unsigned short)(u.w >> 16));
        }
    }
    __syncthreads();

    float* om = out + (size_t)b * DOUT * 3;
    float* os = om + (size_t)B * DOUT * 3;
    float* oa = os + (size_t)B * DOUT * 3;

    const int nq = (t == T - 1) ? 3 : 4;   // last chunk: 12 dims
    for (int q = 0; q < nq; ++q) {
        float bufm[12], bufs[12], bufa[12];
#pragma unroll
        for (int dl4 = 0; dl4 < 4; ++dl4) {
            const int dl = q * 4 + dl4;
            const float xv = xT[(size_t)(dstart + dl) * B + b];

            float acc[9];
#pragma unroll
            for (int k = 0; k < 9; ++k) acc[k] = 0.f;
            const unsigned* vb = vsh + dl * (32 * 12);
#pragma unroll
            for (int hp = 0; hp < 32; ++hp) {
#if HAS_DOT2
                half2_t h2 = __builtin_amdgcn_cvt_pkrtz(fmaxf(a[2 * hp], 0.f),
                                                        fmaxf(a[2 * hp + 1], 0.f));
                const uint4 u0 = *(const uint4*)(vb + hp * 12);
                const uint4 u1 = *(const uint4*)(vb + hp * 12 + 4);
                const unsigned u2 = vb[hp * 12 + 8];
                acc[0] = __builtin_amdgcn_fdot2(h2, as_h2(u0.x), acc[0], false);
                acc[1] = __builtin_amdgcn_fdot2(h2, as_h2(u0.y), acc[1], false);
                acc[2] = __builtin_amdgcn_fdot2(h2, as_h2(u0.z), acc[2], false);
                acc[3] = __builtin_amdgcn_fdot2(h2, as_h2(u0.w), acc[3], false);
                acc[4] = __builtin_amdgcn_fdot2(h2, as_h2(u1.x), acc[4], false);
                acc[5] = __builtin_amdgcn_fdot2(h2, as_h2(u1.y), acc[5], false);
                acc[6] = __builtin_amdgcn_fdot2(h2, as_h2(u1.z), acc[6], false);
                acc[7] = __builtin_amdgcn_fdot2(h2, as_h2(u1.w), acc[7], false);
                acc[8] = __builtin_amdgcn_fdot2(h2, as_h2(u2),   acc[8], false);
#else
                const float h0 = fmaxf(a[2 * hp], 0.f);
                const float h1 = fmaxf(a[2 * hp + 1], 0.f);
                const uint4 u0 = *(const uint4*)(vb + hp * 12);
                const uint4 u1 = *(const uint4*)(vb + hp * 12 + 4);
                const unsigned u2 = vb[hp * 12 + 8];
                unsigned uu[9] = {u0.x, u0.y, u0.z, u0.w, u1.x, u1.y, u1.z, u1.w, u2};
#pragma unroll
                for (int k = 0; k < 9; ++k) {
                    acc[k] = fmaf(h1, h2f_u((unsigned short)(uu[k] >> 16)),
                             fmaf(h0, h2f_u((unsigned short)(uu[k] & 0xffff)), acc[k]));
                }
#endif
            }
            // mean
            bufm[dl4 * 3 + 0] = acc[0] + bsh[dl * 9 + 0];
            bufm[dl4 * 3 + 1] = acc[1] + bsh[dl * 9 + 1];
            bufm[dl4 * 3 + 2] = acc[2] + bsh[dl * 9 + 2];
            // std = sigmoid(z)*2 + 0.6
#pragma unroll
            for (int k = 0; k < 3; ++k) {
                const float z = acc[3 + k] + bsh[dl * 9 + 3 + k];
                bufs[dl4 * 3 + k] = 2.f * __builtin_amdgcn_rcpf(1.f + __expf(-z)) + 0.6f;
            }
            // alpha = softmax
            {
                const float z0 = acc[6] + bsh[dl * 9 + 6];
                const float z1 = acc[7] + bsh[dl * 9 + 7];
                const float z2 = acc[8] + bsh[dl * 9 + 8];
                const float mx = fmaxf(z0, fmaxf(z1, z2));
                const float e0 = __expf(z0 - mx);
                const float e1 = __expf(z1 - mx);
                const float e2 = __expf(z2 - mx);
                const float inv = __builtin_amdgcn_rcpf(e0 + e1 + e2);
                bufa[dl4 * 3 + 0] = e0 * inv;
                bufa[dl4 * 3 + 1] = e1 * inv;
                bufa[dl4 * 3 + 2] = e2 * inv;
            }
            // a[h] += x * W[h]
            const float* wp = wsh + dl * H;
#pragma unroll
            for (int h = 0; h < H; h += 4) {
                float4 wv = *(const float4*)(wp + h);
                a[h]     = fmaf(xv, wv.x, a[h]);
                a[h + 1] = fmaf(xv, wv.y, a[h + 1]);
                a[h + 2] = fmaf(xv, wv.z, a[h + 2]);
                a[h + 3] = fmaf(xv, wv.w, a[h + 3]);
            }
        }
        // flush quarter: i-base = 16t + 4q -> float offset 48t+12q (48B aligned)
        const size_t off = (size_t)(16 * t + 4 * q) * 3;
#pragma unroll
        for (int qd = 0; qd < 3; ++qd) {
            *(float4*)(om + off + qd * 4) = make_float4(bufm[qd*4], bufm[qd*4+1], bufm[qd*4+2], bufm[qd*4+3]);
            *(float4*)(os + off + qd * 4) = make_float4(bufs[qd*4], bufs[qd*4+1], bufs[qd*4+2], bufs[qd*4+3]);
            *(float4*)(oa + off + qd * 4) = make_float4(bufa[qd*4], bufa[qd*4+1], bufa[qd*4+2], bufa[qd*4+3]);
        }
    }
}

// ---------------------------------------------------------------------------
extern "C" void kernel_launch(void* const* d_in, const int* in_sizes, int n_in,
                              void* d_out, int out_size, void* d_ws, size_t ws_size,
                              hipStream_t stream) {
    const float* x  = (const float*)d_in[0];   // [B, D]
    const float* W  = (const float*)d_in[1];   // [H, D]
    const float* c  = (const float*)d_in[2];   // [1, H]
    const float* Vm = (const float*)d_in[3];   // [D, H, K]
    const float* Va = (const float*)d_in[4];   // [D, H, K]
    const float* Vs = (const float*)d_in[5];   // [D, H, K]
    const float* bm = (const float*)d_in[6];   // [D, K]
    const float* ba = (const float*)d_in[7];   // [D, K]
    const float* bs = (const float*)d_in[8];   // [D, K]
    float* out = (float*)d_out;

    float* wsf = (float*)d_ws;
    unsigned short* S = (unsigned short*)(wsf + WS_S);
    unsigned* Vp = (unsigned*)(wsf + WS_VP);
    float* Wt = wsf + WS_WT;
    float* xT = wsf + WS_XT;

    k_pack<<<dim3(D * 32 / 256), dim3(256), 0, stream>>>(Vm, Va, Vs, Vp);
    k_wt<<<dim3(D / 64), dim3(256), 0, stream>>>(W, Wt);
    k_xt<<<dim3(D / 64, B / 64), dim3(256), 0, stream>>>(x, xT);
    k_prefix<<<dim3(B / 8), dim3(512), 0, stream>>>(x, W, c, S);
    k_main<<<dim3(B / 256, T), dim3(256), 0, stream>>>(xT, S, Vp, Wt, bm, ba, bs, out);
}

// Round 8
// 163.342 us; speedup vs baseline: 3.9340x; 1.1078x over previous
//
#include <hip/hip_runtime.h>
#include <hip/hip_bf16.h>

// Problem constants
#define B 2048
#define D 1024
#define H 64
#define DOUT (D - 4)      // 1020
#define T 64              // chunks; chunk t anchored at dstart = 16t+4
#define DC 16             // dims per chunk (last chunk: 12)

typedef __attribute__((ext_vector_type(8))) short short8;
typedef __attribute__((ext_vector_type(4))) float f32x4;

// Workspace layout (float slots):
//   S   : T*B*H f16 = 8,388,608 halfs -> 4,194,304 float slots
//   VbP : D*2ks*64lane uint4 (bf16 A-frags, 12-row-padded V) = 524,288 float slots
#define WS_S  0
#define WS_VB (T * B * H / 2)

__device__ __forceinline__ unsigned short f2h_u(float f) {
    union { _Float16 h; unsigned short u; } v; v.h = (_Float16)f; return v.u;
}
__device__ __forceinline__ float h2f_u(unsigned short s) {
    union { unsigned short u; _Float16 h; } v; v.u = s; return (float)v.h;
}
__device__ __forceinline__ unsigned short f2bf(float f) {
    union { float f; unsigned int u; } v; v.f = f;
    unsigned int r = (v.u + 0x7FFFu + ((v.u >> 16) & 1u)) >> 16;  // RNE
    return (unsigned short)r;
}
__device__ __forceinline__ unsigned cvtpk_bf16(float lo, float hi) {
    unsigned d;
    asm("v_cvt_pk_bf16_f32 %0, %1, %2" : "=v"(d) : "v"(lo), "v"(hi));
    return d;
}

union U8 { unsigned u[4]; short8 s; };

// ---------------------------------------------------------------------------
// Pack V into MFMA A-frag layout (bf16), 12 padded m-rows:
// m: 0-2 = Vmean k, 4-6 = Vstd k, 8-10 = Valpha k, else 0.
// VbP[(d*2+ks)*64 + lane] = uint4 of 8 bf16: j=0..7 -> V[d][h=ks*32+(l>>4)*8+j][m(l&15)]
// One thread per (d, ks, lane). grid D*2*64/256.
// ---------------------------------------------------------------------------
__global__ __launch_bounds__(256) void k_pack(const float* __restrict__ Vm,
                                              const float* __restrict__ Va,
                                              const float* __restrict__ Vs,
                                              uint4* __restrict__ VbP) {
    const int idx = blockIdx.x * 256 + threadIdx.x;   // (d*2+ks)*64 + l
    const int l   = idx & 63;
    const int ks  = (idx >> 6) & 1;
    const int d   = idx >> 7;
    const int m   = l & 15;
    const int h0  = ks * 32 + (l >> 4) * 8;

    const float* src = nullptr;
    int k = 0;
    if (m < 3)                { src = Vm; k = m; }
    else if (m >= 4 && m < 7) { src = Vs; k = m - 4; }
    else if (m >= 8 && m < 11){ src = Va; k = m - 8; }

    unsigned u[4] = {0u, 0u, 0u, 0u};
    if (src) {
#pragma unroll
        for (int i = 0; i < 4; ++i) {
            unsigned short lo = f2bf(src[((size_t)d * H + h0 + 2 * i) * 3 + k]);
            unsigned short hi = f2bf(src[((size_t)d * H + h0 + 2 * i + 1) * 3 + k]);
            u[i] = ((unsigned)hi << 16) | lo;
        }
    }
    VbP[idx] = make_uint4(u[0], u[1], u[2], u[3]);
}

// ---------------------------------------------------------------------------
// Prefix: wave per b (lane = h). W tiles staged in LDS [h][d]; x broadcast via
// LDS. Emit f16 checkpoint S[t][b][h] at d = 16t+4. grid (B/8), block 512.
// ---------------------------------------------------------------------------
__global__ __launch_bounds__(512) void k_prefix(const float* __restrict__ x,
                                                const float* __restrict__ W,
                                                const float* __restrict__ cvec,
                                                unsigned short* __restrict__ S) {
    __shared__ float wt[64 * 68];
    __shared__ float xl[8 * 64];
    const int tid  = threadIdx.x;
    const int lane = tid & 63;      // h
    const int w    = tid >> 6;
    const int b    = blockIdx.x * 8 + w;

    float run = cvec[lane];
    for (int c = 0; c < 16; ++c) {
        __syncthreads();
        {
            const int h = tid >> 3, dc = (tid & 7) * 8;
            const float* src = W + (size_t)h * D + c * 64 + dc;
            float4 v0 = *(const float4*)src;
            float4 v1 = *(const float4*)(src + 4);
            float* dst = wt + h * 68 + dc;
            *(float4*)dst = v0;
            *(float4*)(dst + 4) = v1;
        }
        xl[w * 64 + lane] = x[(size_t)b * D + c * 64 + lane];
        __syncthreads();
#pragma unroll
        for (int dg = 0; dg < 16; ++dg) {
            if ((dg & 3) == 1) {   // d_local = dg*4 in {4,20,36,52} -> emit
                const int t = 4 * c + (dg >> 2);
                S[((size_t)t * B + b) * H + lane] = f2h_u(run);
            }
            float4 w4 = *(const float4*)(wt + lane * 68 + dg * 4);
            float4 x4 = *(const float4*)(xl + w * 64 + dg * 4);
            run = fmaf(x4.x, w4.x, run);
            run = fmaf(x4.y, w4.y, run);
            run = fmaf(x4.z, w4.z, run);
            run = fmaf(x4.w, w4.w, run);
        }
    }
}

// ---------------------------------------------------------------------------
// Main (MFMA): block = 4 waves = 256 b at chunk t (dims 16t+4..+15).
// Per wave: 64 b via 4 n-tiles (bt). State a[4bt][2ks][8j] f32 in regs.
// Per d: B-frag = relu(a)->bf16 (cvt_pk), A-frag = V from LDS, bias as C-in,
// 8 MFMA (4bt x 2ks chained), per-lane epilogue by quarter (m-row group),
// reg-buffered output, 48B-aligned float4 flush per 4 dims.
// grid (B/256, T), block 256.
// ---------------------------------------------------------------------------
__global__ __launch_bounds__(256, 2) void k_main(const float* __restrict__ x,
                                                 const float* __restrict__ W,
                                                 const unsigned short* __restrict__ S,
                                                 const uint4* __restrict__ VbP,
                                                 const float* __restrict__ bm,
                                                 const float* __restrict__ ba,
                                                 const float* __restrict__ bs,
                                                 float* __restrict__ out) {
    __shared__ short8 vbsh[DC][2][64];   // 32 KB  A-frags
    __shared__ float  wshf[DC][64];      //  4 KB  W[d][h]
    __shared__ float  xsf[DC][256];      // 16 KB  x[d][b_local]
    __shared__ float  bshf[DC][16];      //  1 KB  bias by m-row

    const int tid    = threadIdx.x;
    const int lane   = tid & 63;
    const int w      = tid >> 6;
    const int t      = blockIdx.y;
    const int bx     = blockIdx.x;
    const int dstart = 16 * t + 4;
    const int dvalid = D - dstart;       // 16, except 12 at t=63
    const int r      = lane & 15;        // n within tile (b)
    const int qq     = lane >> 4;        // quarter -> m-row group / k-slice

    // ---- stage chunk ----
    {
        const uint4* vsrc = VbP + (size_t)dstart * 128;
        uint4* vdst = (uint4*)vbsh;
#pragma unroll
        for (int q = 0; q < 8; ++q) {
            const int j = q * 256 + tid;
            if (j < dvalid * 128) vdst[j] = vsrc[j];
        }
        {   // W: thread (h = tid>>2, part = tid&3) reads 16B row-chunk, transposes
            const int h = tid >> 2, part = tid & 3;
            if (dstart + part * 4 < D) {
                float4 v = *(const float4*)(W + (size_t)h * D + dstart + part * 4);
                wshf[part * 4 + 0][h] = v.x;
                wshf[part * 4 + 1][h] = v.y;
                wshf[part * 4 + 2][h] = v.z;
                wshf[part * 4 + 3][h] = v.w;
            }
        }
        {   // x: thread = local b, 4x float4 coalesced row read, transpose to [d][b]
            const float* xr = x + (size_t)(bx * 256 + tid) * D + dstart;
#pragma unroll
            for (int part = 0; part < 4; ++part) {
                if (dstart + part * 4 < D) {
                    float4 v = *(const float4*)(xr + part * 4);
                    xsf[part * 4 + 0][tid] = v.x;
                    xsf[part * 4 + 1][tid] = v.y;
                    xsf[part * 4 + 2][tid] = v.z;
                    xsf[part * 4 + 3][tid] = v.w;
                }
            }
        }
        {   // bias: thread -> (dl, m)
            const int dl = tid >> 4, m = tid & 15;
            const int d = dstart + dl;
            float v = 0.f;
            if (d < D) {
                if (m < 3)                 v = bm[(size_t)d * 3 + m];
                else if (m >= 4 && m < 7)  v = bs[(size_t)d * 3 + m - 4];
                else if (m >= 8 && m < 11) v = ba[(size_t)d * 3 + m - 8];
            }
            bshf[dl][m] = v;
        }
    }

    // ---- load f16 checkpoints into B-frag-layout state a[bt][ks][j] ----
    float a_[4][2][8];
#pragma unroll
    for (int bt = 0; bt < 4; ++bt) {
#pragma unroll
        for (int ks = 0; ks < 2; ++ks) {
            const unsigned short* sp =
                S + ((size_t)t * B + bx * 256 + w * 64 + bt * 16 + r) * H + ks * 32 + qq * 8;
            uint4 u = *(const uint4*)sp;
            a_[bt][ks][0] = h2f_u((unsigned short)(u.x & 0xffff));
            a_[bt][ks][1] = h2f_u((unsigned short)(u.x >> 16));
            a_[bt][ks][2] = h2f_u((unsigned short)(u.y & 0xffff));
            a_[bt][ks][3] = h2f_u((unsigned short)(u.y >> 16));
            a_[bt][ks][4] = h2f_u((unsigned short)(u.z & 0xffff));
            a_[bt][ks][5] = h2f_u((unsigned short)(u.z >> 16));
            a_[bt][ks][6] = h2f_u((unsigned short)(u.w & 0xffff));
            a_[bt][ks][7] = h2f_u((unsigned short)(u.w >> 16));
        }
    }
    __syncthreads();

    const int nq = (t == T - 1) ? 3 : 4;
    for (int qd = 0; qd < nq; ++qd) {
        float buf[4][12];
#pragma unroll
        for (int d4 = 0; d4 < 4; ++d4) {
            const int dl = qd * 4 + d4;

            // B-frags: relu + pack to bf16
            U8 bf[4][2];
#pragma unroll
            for (int bt = 0; bt < 4; ++bt)
#pragma unroll
                for (int ks = 0; ks < 2; ++ks)
#pragma unroll
                    for (int i = 0; i < 4; ++i)
                        bf[bt][ks].u[i] = cvtpk_bf16(fmaxf(a_[bt][ks][2 * i], 0.f),
                                                     fmaxf(a_[bt][ks][2 * i + 1], 0.f));

            // A-frags + bias C-in
            short8 A0 = vbsh[dl][0][lane];
            short8 A1 = vbsh[dl][1][lane];
            f32x4 bias4 = ((const f32x4*)&bshf[dl][0])[qq];

            // 8 MFMA: 4 bt x 2 chained K-steps
            f32x4 acc[4];
#pragma unroll
            for (int bt = 0; bt < 4; ++bt) {
                acc[bt] = __builtin_amdgcn_mfma_f32_16x16x32_bf16(A0, bf[bt][0].s, bias4, 0, 0, 0);
                acc[bt] = __builtin_amdgcn_mfma_f32_16x16x32_bf16(A1, bf[bt][1].s, acc[bt], 0, 0, 0);
            }

            // epilogue per lane-quarter: q0 mean (raw), q1 std, q2 alpha, q3 idle
#pragma unroll
            for (int bt = 0; bt < 4; ++bt) {
                float z0 = acc[bt][0], z1 = acc[bt][1], z2 = acc[bt][2];
                float o0 = z0, o1 = z1, o2 = z2;
                if (qq == 1) {
                    o0 = 2.f * __builtin_amdgcn_rcpf(1.f + __expf(-z0)) + 0.6f;
                    o1 = 2.f * __builtin_amdgcn_rcpf(1.f + __expf(-z1)) + 0.6f;
                    o2 = 2.f * __builtin_amdgcn_rcpf(1.f + __expf(-z2)) + 0.6f;
                } else if (qq == 2) {
                    float mx = fmaxf(z0, fmaxf(z1, z2));
                    float e0 = __expf(z0 - mx);
                    float e1 = __expf(z1 - mx);
                    float e2 = __expf(z2 - mx);
                    float inv = __builtin_amdgcn_rcpf(e0 + e1 + e2);
                    o0 = e0 * inv; o1 = e1 * inv; o2 = e2 * inv;
                }
                buf[bt][d4 * 3 + 0] = o0;
                buf[bt][d4 * 3 + 1] = o1;
                buf[bt][d4 * 3 + 2] = o2;
            }

            // a-update: a[bt][ks][j] += x[b(bt)] * W[h(ks,qq,j)]
            float4 w0a = *(const float4*)&wshf[dl][qq * 8];
            float4 w0b = *(const float4*)&wshf[dl][qq * 8 + 4];
            float4 w1a = *(const float4*)&wshf[dl][32 + qq * 8];
            float4 w1b = *(const float4*)&wshf[dl][32 + qq * 8 + 4];
#pragma unroll
            for (int bt = 0; bt < 4; ++bt) {
                const float xv = xsf[dl][w * 64 + bt * 16 + r];
                a_[bt][0][0] = fmaf(xv, w0a.x, a_[bt][0][0]);
                a_[bt][0][1] = fmaf(xv, w0a.y, a_[bt][0][1]);
                a_[bt][0][2] = fmaf(xv, w0a.z, a_[bt][0][2]);
                a_[bt][0][3] = fmaf(xv, w0a.w, a_[bt][0][3]);
                a_[bt][0][4] = fmaf(xv, w0b.x, a_[bt][0][4]);
                a_[bt][0][5] = fmaf(xv, w0b.y, a_[bt][0][5]);
                a_[bt][0][6] = fmaf(xv, w0b.z, a_[bt][0][6]);
                a_[bt][0][7] = fmaf(xv, w0b.w, a_[bt][0][7]);
                a_[bt][1][0] = fmaf(xv, w1a.x, a_[bt][1][0]);
                a_[bt][1][1] = fmaf(xv, w1a.y, a_[bt][1][1]);
                a_[bt][1][2] = fmaf(xv, w1a.z, a_[bt][1][2]);
                a_[bt][1][3] = fmaf(xv, w1a.w, a_[bt][1][3]);
                a_[bt][1][4] = fmaf(xv, w1b.x, a_[bt][1][4]);
                a_[bt][1][5] = fmaf(xv, w1b.y, a_[bt][1][5]);
                a_[bt][1][6] = fmaf(xv, w1b.z, a_[bt][1][6]);
                a_[bt][1][7] = fmaf(xv, w1b.w, a_[bt][1][7]);
            }
        }

        // flush: 48B-aligned float4 runs; i0 = 16t + 4qd
        if (qq < 3) {
            float* ob = out + (size_t)qq * ((size_t)B * DOUT * 3);
            const size_t ioff = (size_t)(16 * t + 4 * qd) * 3;
#pragma unroll
            for (int bt = 0; bt < 4; ++bt) {
                float* p = ob + (size_t)(bx * 256 + w * 64 + bt * 16 + r) * (DOUT * 3) + ioff;
                *(float4*)(p + 0) = make_float4(buf[bt][0], buf[bt][1], buf[bt][2], buf[bt][3]);
                *(float4*)(p + 4) = make_float4(buf[bt][4], buf[bt][5], buf[bt][6], buf[bt][7]);
                *(float4*)(p + 8) = make_float4(buf[bt][8], buf[bt][9], buf[bt][10], buf[bt][11]);
            }
        }
    }
}

// ---------------------------------------------------------------------------
extern "C" void kernel_launch(void* const* d_in, const int* in_sizes, int n_in,
                              void* d_out, int out_size, void* d_ws, size_t ws_size,
                              hipStream_t stream) {
    const float* x  = (const float*)d_in[0];   // [B, D]
    const float* W  = (const float*)d_in[1];   // [H, D]
    const float* c  = (const float*)d_in[2];   // [1, H]
    const float* Vm = (const float*)d_in[3];   // [D, H, K]
    const float* Va = (const float*)d_in[4];   // [D, H, K]
    const float* Vs = (const float*)d_in[5];   // [D, H, K]
    const float* bm = (const float*)d_in[6];   // [D, K]
    const float* ba = (const float*)d_in[7];   // [D, K]
    const float* bs = (const float*)d_in[8];   // [D, K]
    float* out = (float*)d_out;

    float* wsf = (float*)d_ws;
    unsigned short* S = (unsigned short*)(wsf + WS_S);
    uint4* VbP = (uint4*)(wsf + WS_VB);

    k_pack<<<dim3(D * 2 * 64 / 256), dim3(256), 0, stream>>>(Vm, Va, Vs, VbP);
    k_prefix<<<dim3(B / 8), dim3(512), 0, stream>>>(x, W, c, S);
    k_main<<<dim3(B / 256, T), dim3(256), 0, stream>>>(x, W, S, VbP, bm, ba, bs, out);
}